// Round 13
// baseline (512.412 us; speedup 1.0000x reference)
//
#include <hip/hip_runtime.h>

// GraphConvBlock, v13 = v12 (reg-weights, barrier-free loop; best 107.7us) +
//  (i) split act staging: rows 0-3 in head; rows 4-5 committed from global
//      (L2-warm) at tail of tap 0, sealed by ONE barrier at top of t=3
//      (first read of rows 4-5). Head shrinks 1/3, no extra VGPRs.
//  (ii) symmetric half-exchange K-reduction + all-wave epilogue: kh=0 sends
//      p{2,3}/keeps p{0,1}; kh=1 sends p{0,1}/keeps p{2,3}; both halves
//      reduce + store concurrently (no idle half-CU tail).

typedef __bf16 bf16x8 __attribute__((ext_vector_type(8)));
typedef float f32x4 __attribute__((ext_vector_type(4)));

union U4 { uint4 u; bf16x8 b; };

__device__ inline unsigned pk_bf16(float lo, float hi) {
  unsigned r;
  asm volatile("v_cvt_pk_bf16_f32 %0, %1, %2" : "=v"(r) : "v"(lo), "v"(hi));
  return r;
}

__device__ inline unsigned addpk(unsigned a, unsigned b) {
  float alo = __builtin_bit_cast(float, a << 16);
  float ahi = __builtin_bit_cast(float, a & 0xFFFF0000u);
  float blo = __builtin_bit_cast(float, b << 16);
  float bhi = __builtin_bit_cast(float, b & 0xFFFF0000u);
  return pk_bf16(alo + blo, ahi + bhi);
}

__device__ inline uint4 addpk4(uint4 a, uint4 b) {
  return make_uint4(addpk(a.x, b.x), addpk(a.y, b.y), addpk(a.z, b.z), addpk(a.w, b.w));
}

#define WB_WORDS 479232

// ---------------- fused setup kernel (v12 layout, unchanged) ------------------
__global__ __launch_bounds__(512) void setup_all(
    const float* __restrict__ x, const float* __restrict__ W0,
    const float* __restrict__ Wn, unsigned* __restrict__ B0,
    unsigned* __restrict__ B1, unsigned* __restrict__ B2,
    unsigned* __restrict__ T, unsigned* __restrict__ Wb) {
  __shared__ float xl[2 * 64 * 65];
  const int tid = threadIdx.x;
  const int bid = blockIdx.x;
  const int n = bid & 7;

#pragma unroll
  for (int it = 0; it < 4; ++it) {
    unsigned gid = (unsigned)bid * 512 + tid + it * 131072u;
    if (gid < WB_WORDS) {
      const float* src;
      int CIN, c, w;
      if (gid < 36864) {
        src = W0; CIN = 64;
        c = gid >> 11; w = gid & 2047;
      } else {
        unsigned g2 = gid - 36864;
        int s = g2 / 73728; unsigned r2 = g2 % 73728;
        src = Wn + (size_t)s * 147456; CIN = 128;
        c = r2 >> 12; w = r2 & 4095;
      }
      int och = c / 9, tap = c % 9;
      int dy = tap / 3, dx = tap % 3;
      int f = w >> 8;                       // frag index
      int nkc = CIN / 32;                   // frags per m (2 or 4)
      int m = f / nkc, kc = f % nkc;
      int r8 = w & 255;
      int lane = r8 >> 2, wq = r8 & 3;
      int oc = och * 64 + m * 16 + (lane & 15);
      int icp = kc * 16 + (lane >> 4) * 4 + wq;
      size_t base = (((size_t)oc * CIN + 2 * icp) * 3 + dy) * 3 + dx;
      Wb[gid] = pk_bf16(src[base], src[base + 9]);
    }
  }

  {
    unsigned gid = (unsigned)bid * 512 + tid;
    if (gid < 116480) {
      unsigned* buf; int CW; unsigned u;
      if (gid < 99840) {
        buf = gid < 33280 ? B0 : (gid < 66560 ? B1 : B2);
        u = gid % 33280; CW = 64;
      } else {
        buf = T; u = gid - 99840; CW = 32;
      }
      int per_n = 65 * CW;
      int nn = u / per_n;
      unsigned v = u % per_n;
      int pix = (v * 4) / CW, cw = (v * 4) % CW;
      int row, col;
      if (pix < 66) { row = 0; col = pix; }
      else if (pix < 132) { row = 65; col = pix - 66; }
      else if (pix < 196) { row = pix - 131; col = 0; }
      else { row = pix - 195; col = 65; }
      *(uint4*)&buf[((((size_t)nn * 66 + row) * 66 + col) * CW) + cw] =
          make_uint4(0, 0, 0, 0);
    }
  }

  {
    int hh = bid >> 3;
    int sub = tid >> 8;
    int t8 = tid & 255;
    int h = hh * 2 + sub;
#pragma unroll
    for (int k = 0; k < 16; ++k) {
      int idx = t8 + k * 256;
      int ic = idx >> 6, w = idx & 63;
      xl[(sub * 64 + w) * 65 + ic] = x[(((size_t)n * 64 + ic) * 64 + h) * 64 + w];
    }
    __syncthreads();
#pragma unroll
    for (int k = 0; k < 8; ++k) {
      int idx = t8 + k * 256;
      int w = idx >> 5, icp = idx & 31;
      unsigned v = pk_bf16(xl[(sub * 64 + w) * 65 + icp * 2],
                           xl[(sub * 64 + w) * 65 + icp * 2 + 1]);
      int wp = w + 1;
      int pos = icp ^ ((wp & 7) << 2);
      T[(((size_t)n * 66 + (h + 1)) * 66 + wp) * 32 + pos] = v;
    }
  }
}

// ---------------- unified conv stage (reg-weights, barrier-light loop) --------
template <int CIN, bool DUAL, bool OUTF32>
__global__ __launch_bounds__(512, 2) void conv_stage(
    const unsigned* __restrict__ in0, const unsigned* __restrict__ in1,
    const unsigned* __restrict__ wb, const float* __restrict__ bias,
    float bmult, void* __restrict__ outp) {
  constexpr int WPP = CIN / 2;          // u32 words per pixel
  constexpr int CHW = 64 * WPP;         // words per weight chunk
  constexpr int CH_U4 = CHW / 4;
  constexpr int NKC_TOT = WPP / 16;     // kc values total (2 or 4)
  constexpr int KCW = NKC_TOT / 2;      // kc per kh (1 or 2)
  constexpr int ROWW = 66 * WPP;
  constexpr int ACTW = 6 * ROWW;
  constexpr int ALDS_W = (ACTW > 16384) ? ACTW : 16384;
  constexpr int R4_U4 = 4 * ROWW / 4;   // uint4 in rows 0..3
  constexpr int R2_U4 = 2 * ROWW / 4;   // uint4 in rows 4..5
  constexpr int AJ4 = (R4_U4 + 511) / 512;
  constexpr int LJ = (R2_U4 + 511) / 512;

  __shared__ unsigned Alds[ALDS_W];

  const int tid = threadIdx.x;
  const int lane = tid & 63;
  const int wav = tid >> 6;
  const int wr = wav >> 1;              // output row 0..3
  const int kh = wav & 1;               // K half
  const int l15 = lane & 15, q = lane >> 4;
  const int bid = blockIdx.x;
  const int n = bid & 7;                // same-n -> same XCD (L2 locality)
  const int ochalf = (bid >> 3) & 1;
  const int h0 = (bid >> 4) * 4;

  const uint4* wg = (const uint4*)(wb + (size_t)ochalf * 9 * CHW);
  const size_t abase = ((size_t)n * 66 + h0) * ROWW;
  const uint4* g0 = (const uint4*)(in0 + abase);
  const uint4* g1 = (const uint4*)(in1 + abase);

  // ---- head: stage only rows 0..3 (fused child-sum) ----
#pragma unroll
  for (int j = 0; j < AJ4; ++j) {
    int i = tid + j * 512;
    if (i < R4_U4) {
      uint4 v = g0[i];
      if (DUAL) v = addpk4(v, g1[i]);
      *(uint4*)&Alds[4 * i] = v;
    }
  }

  // prefetch tap 0 A-frags into regs (overlaps staging stores)
  uint4 wcur[4][KCW], wnxt[4][KCW];
#pragma unroll
  for (int m = 0; m < 4; ++m)
#pragma unroll
    for (int kc2 = 0; kc2 < KCW; ++kc2)
      wcur[m][kc2] = wg[(m * NKC_TOT + kh * KCW + kc2) * 64 + lane];

  __syncthreads();  // rows 0..3 visible

  f32x4 acc[4][4];
#pragma unroll
  for (int m = 0; m < 4; ++m)
#pragma unroll
    for (int p = 0; p < 4; ++p) acc[m][p] = (f32x4)0.f;

#pragma unroll
  for (int t = 0; t < 9; ++t) {
    // seal rows 4,5 before their first read (t=3: dy=1 -> row wr+1 up to 4)
    if (t == 3) {
      asm volatile("s_waitcnt lgkmcnt(0)" ::: "memory");
      __builtin_amdgcn_s_barrier();
      __builtin_amdgcn_sched_barrier(0);
    }

    // prefetch next tap's A-frags (compiler emits counted vmcnt before use)
    if (t < 8) {
#pragma unroll
      for (int m = 0; m < 4; ++m)
#pragma unroll
        for (int kc2 = 0; kc2 < KCW; ++kc2)
          wnxt[m][kc2] =
              wg[(t + 1) * CH_U4 + (m * NKC_TOT + kh * KCW + kc2) * 64 + lane];
    }

    const int dy = t / 3, dx = t % 3;
    const int arow = (wr + dy) * 66;

    __builtin_amdgcn_s_setprio(1);
#pragma unroll
    for (int kc2 = 0; kc2 < KCW; ++kc2) {
      const int kc = kh * KCW + kc2;
      bf16x8 a[4];
#pragma unroll
      for (int m = 0; m < 4; ++m) {
        U4 u; u.u = wcur[m][kc2]; a[m] = u.b;
      }
#pragma unroll
      for (int p = 0; p < 4; ++p) {
        int col = p * 16 + l15 + dx;
        U4 u;
        u.u = *(const uint4*)&Alds[(arow + col) * WPP +
                                   ((kc * 16 + q * 4) ^ ((col & 7) << 2))];
        bf16x8 b = u.b;
#pragma unroll
        for (int m = 0; m < 4; ++m)
          acc[m][p] =
              __builtin_amdgcn_mfma_f32_16x16x32_bf16(a[m], b, acc[m][p], 0, 0, 0);
      }
    }
    __builtin_amdgcn_s_setprio(0);

    // tail of tap 0: commit rows 4,5 straight from global (L2-warm), first
    // read at t=3 -> ~2 taps of latency slack; sealed by the t=3 barrier.
    if (t == 0) {
#pragma unroll
      for (int j = 0; j < LJ; ++j) {
        int i = tid + j * 512;
        if (i < R2_U4) {
          uint4 v = g0[R4_U4 + i];
          if (DUAL) v = addpk4(v, g1[R4_U4 + i]);
          *(uint4*)&Alds[4 * (R4_U4 + i)] = v;
        }
      }
    }

    // static dbuf swap (fully unrolled -> registers)
#pragma unroll
    for (int m = 0; m < 4; ++m)
#pragma unroll
      for (int kc2 = 0; kc2 < KCW; ++kc2) wcur[m][kc2] = wnxt[m][kc2];
  }

  // ---- symmetric half-exchange K reduction (both halves stay active) ----
  // kh=0 owns p{0,1}, sends p{2,3}; kh=1 owns p{2,3}, sends p{0,1}.
  __syncthreads();  // act reads done before overwrite
  float* R = (float*)Alds;
  {
    const int psend = kh ? 0 : 2;
#pragma unroll
    for (int m = 0; m < 4; ++m)
#pragma unroll
      for (int pp = 0; pp < 2; ++pp)
        *(f32x4*)&R[(((wr * 2 + kh) * 8) + m * 2 + pp) * 256 + lane * 4] =
            acc[m][psend + pp];
  }
  __syncthreads();
  const int pown = kh ? 2 : 0;
  {
#pragma unroll
    for (int m = 0; m < 4; ++m)
#pragma unroll
      for (int pp = 0; pp < 2; ++pp) {
        f32x4 o = *(const f32x4*)&R[(((wr * 2 + (1 - kh)) * 8) + m * 2 + pp) * 256 +
                                    lane * 4];
        acc[m][pown + pp] += o;
      }
  }

  // ---- epilogue: every wave writes its owned 2 p-frags of row h0+wr ----
  const int obase = ochalf * 64;
  if (OUTF32) {
    float* out = (float*)outp;
#pragma unroll
    for (int m = 0; m < 4; ++m) {
      int oc0 = obase + m * 16 + q * 4;
      float4 bb = *(const float4*)&bias[oc0];
#pragma unroll
      for (int pp = 0; pp < 2; ++pp) {
        int p = pown + pp;
        int w = p * 16 + l15;
#pragma unroll
        for (int j = 0; j < 4; ++j)
          out[(((size_t)n * 128 + oc0 + j) * 64 + (h0 + wr)) * 64 + w] =
              acc[m][p][j] + ((const float*)&bb)[j] * bmult;
      }
    }
  } else {
    unsigned* out = (unsigned*)outp;
#pragma unroll
    for (int m = 0; m < 4; ++m) {
      int oc0 = obase + m * 16 + q * 4;
      float4 bb = *(const float4*)&bias[oc0];
      int icp0 = oc0 >> 1;
#pragma unroll
      for (int pp = 0; pp < 2; ++pp) {
        int p = pown + pp;
        int w = p * 16 + l15;
        int wp = w + 1;
        unsigned lo = pk_bf16(acc[m][p][0] + bb.x * bmult, acc[m][p][1] + bb.y * bmult);
        unsigned hi = pk_bf16(acc[m][p][2] + bb.z * bmult, acc[m][p][3] + bb.w * bmult);
        int pos = icp0 ^ ((wp & 7) << 2);
        size_t base = (((size_t)n * 66 + (h0 + 1 + wr)) * 66 + wp) * 64;
        *(uint2*)&out[base + pos] = make_uint2(lo, hi);
      }
    }
  }
}

// ---------------- launch ------------------------------------------------------
extern "C" void kernel_launch(void* const* d_in, const int* in_sizes, int n_in,
                              void* d_out, int out_size, void* d_ws,
                              size_t ws_size, hipStream_t stream) {
  const float* x = (const float*)d_in[0];
  const float* W0 = (const float*)d_in[1];
  const float* b0 = (const float*)d_in[2];
  const float* Wn = (const float*)d_in[3];
  const float* bn = (const float*)d_in[4];

  const size_t ACTB = (size_t)8 * 66 * 66 * 64;
  const size_t TW = (size_t)8 * 66 * 66 * 32;
  unsigned* B0 = (unsigned*)d_ws;
  unsigned* B1 = B0 + ACTB;
  unsigned* B2 = B1 + ACTB;
  unsigned* T = B2 + ACTB;
  unsigned* Wb = T + TW;

  setup_all<<<256, 512, 0, stream>>>(x, W0, Wn, B0, B1, B2, T, Wb);

  dim3 grid(256), blk(512);
  const unsigned* Wnode = Wb + 36864;
  const size_t NW = 73728;

  // stem: T -> B0
  conv_stage<64, false, false><<<grid, blk, 0, stream>>>(T, T, Wb, b0, 1.f, B0);
  // node1 {0}: B0 -> B1
  conv_stage<128, false, false><<<grid, blk, 0, stream>>>(B0, B0, Wnode, bn + 0, 1.f, B1);
  // node2 {0,1}: B0+B1 -> B2
  conv_stage<128, true, false><<<grid, blk, 0, stream>>>(B0, B1, Wnode + 1 * NW, bn + 128, 2.f, B2);
  // node3 {1,2}: B1+B2 -> B0
  conv_stage<128, true, false><<<grid, blk, 0, stream>>>(B1, B2, Wnode + 2 * NW, bn + 256, 2.f, B0);
  // node4 {2,3}: B2+B0 -> B1
  conv_stage<128, true, false><<<grid, blk, 0, stream>>>(B2, B0, Wnode + 3 * NW, bn + 384, 2.f, B1);
  // node5 {3,4}: B0+B1 -> B2
  conv_stage<128, true, false><<<grid, blk, 0, stream>>>(B0, B1, Wnode + 4 * NW, bn + 512, 2.f, B2);
  // node6 {4,5}: B1+B2 -> d_out (fp32 NCHW)
  conv_stage<128, true, true><<<grid, blk, 0, stream>>>(B1, B2, Wnode + 5 * NW, bn + 640, 2.f, d_out);

  (void)in_sizes; (void)n_in; (void)out_size; (void)ws_size;
}

// Round 14
// 106.969 us; speedup vs baseline: 4.7903x; 4.7903x over previous
//
#include <hip/hip_runtime.h>

// GraphConvBlock, v14 = v13 with the scratch-spill fixed (rule #20):
// reduction + epilogue use wave-uniform kh BRANCHES with compile-time-constant
// acc indices (v13's runtime pown indexing demoted acc[] to scratch ->
// 292MB/dispatch spill traffic, 82us/stage).
//  - split act staging: rows 0-3 head; rows 4-5 committed at tail of tap 0,
//    sealed by one lgkm barrier at top of t=3.
//  - symmetric half-exchange K-reduction; all waves reduce + store.
//  - reg-weights from global (L1-served), barrier-free tap loop (v12 base).

typedef __bf16 bf16x8 __attribute__((ext_vector_type(8)));
typedef float f32x4 __attribute__((ext_vector_type(4)));

union U4 { uint4 u; bf16x8 b; };

__device__ inline unsigned pk_bf16(float lo, float hi) {
  unsigned r;
  asm volatile("v_cvt_pk_bf16_f32 %0, %1, %2" : "=v"(r) : "v"(lo), "v"(hi));
  return r;
}

__device__ inline unsigned addpk(unsigned a, unsigned b) {
  float alo = __builtin_bit_cast(float, a << 16);
  float ahi = __builtin_bit_cast(float, a & 0xFFFF0000u);
  float blo = __builtin_bit_cast(float, b << 16);
  float bhi = __builtin_bit_cast(float, b & 0xFFFF0000u);
  return pk_bf16(alo + blo, ahi + bhi);
}

__device__ inline uint4 addpk4(uint4 a, uint4 b) {
  return make_uint4(addpk(a.x, b.x), addpk(a.y, b.y), addpk(a.z, b.z), addpk(a.w, b.w));
}

#define WB_WORDS 479232

// ---------------- fused setup kernel (v12 layout, unchanged) ------------------
__global__ __launch_bounds__(512) void setup_all(
    const float* __restrict__ x, const float* __restrict__ W0,
    const float* __restrict__ Wn, unsigned* __restrict__ B0,
    unsigned* __restrict__ B1, unsigned* __restrict__ B2,
    unsigned* __restrict__ T, unsigned* __restrict__ Wb) {
  __shared__ float xl[2 * 64 * 65];
  const int tid = threadIdx.x;
  const int bid = blockIdx.x;
  const int n = bid & 7;

#pragma unroll
  for (int it = 0; it < 4; ++it) {
    unsigned gid = (unsigned)bid * 512 + tid + it * 131072u;
    if (gid < WB_WORDS) {
      const float* src;
      int CIN, c, w;
      if (gid < 36864) {
        src = W0; CIN = 64;
        c = gid >> 11; w = gid & 2047;
      } else {
        unsigned g2 = gid - 36864;
        int s = g2 / 73728; unsigned r2 = g2 % 73728;
        src = Wn + (size_t)s * 147456; CIN = 128;
        c = r2 >> 12; w = r2 & 4095;
      }
      int och = c / 9, tap = c % 9;
      int dy = tap / 3, dx = tap % 3;
      int f = w >> 8;
      int nkc = CIN / 32;
      int m = f / nkc, kc = f % nkc;
      int r8 = w & 255;
      int lane = r8 >> 2, wq = r8 & 3;
      int oc = och * 64 + m * 16 + (lane & 15);
      int icp = kc * 16 + (lane >> 4) * 4 + wq;
      size_t base = (((size_t)oc * CIN + 2 * icp) * 3 + dy) * 3 + dx;
      Wb[gid] = pk_bf16(src[base], src[base + 9]);
    }
  }

  {
    unsigned gid = (unsigned)bid * 512 + tid;
    if (gid < 116480) {
      unsigned* buf; int CW; unsigned u;
      if (gid < 99840) {
        buf = gid < 33280 ? B0 : (gid < 66560 ? B1 : B2);
        u = gid % 33280; CW = 64;
      } else {
        buf = T; u = gid - 99840; CW = 32;
      }
      int per_n = 65 * CW;
      int nn = u / per_n;
      unsigned v = u % per_n;
      int pix = (v * 4) / CW, cw = (v * 4) % CW;
      int row, col;
      if (pix < 66) { row = 0; col = pix; }
      else if (pix < 132) { row = 65; col = pix - 66; }
      else if (pix < 196) { row = pix - 131; col = 0; }
      else { row = pix - 195; col = 65; }
      *(uint4*)&buf[((((size_t)nn * 66 + row) * 66 + col) * CW) + cw] =
          make_uint4(0, 0, 0, 0);
    }
  }

  {
    int hh = bid >> 3;
    int sub = tid >> 8;
    int t8 = tid & 255;
    int h = hh * 2 + sub;
#pragma unroll
    for (int k = 0; k < 16; ++k) {
      int idx = t8 + k * 256;
      int ic = idx >> 6, w = idx & 63;
      xl[(sub * 64 + w) * 65 + ic] = x[(((size_t)n * 64 + ic) * 64 + h) * 64 + w];
    }
    __syncthreads();
#pragma unroll
    for (int k = 0; k < 8; ++k) {
      int idx = t8 + k * 256;
      int w = idx >> 5, icp = idx & 31;
      unsigned v = pk_bf16(xl[(sub * 64 + w) * 65 + icp * 2],
                           xl[(sub * 64 + w) * 65 + icp * 2 + 1]);
      int wp = w + 1;
      int pos = icp ^ ((wp & 7) << 2);
      T[(((size_t)n * 66 + (h + 1)) * 66 + wp) * 32 + pos] = v;
    }
  }
}

// ---------------- unified conv stage ------------------------------------------
template <int CIN, bool DUAL, bool OUTF32>
__global__ __launch_bounds__(512, 2) void conv_stage(
    const unsigned* __restrict__ in0, const unsigned* __restrict__ in1,
    const unsigned* __restrict__ wb, const float* __restrict__ bias,
    float bmult, void* __restrict__ outp) {
  constexpr int WPP = CIN / 2;
  constexpr int CHW = 64 * WPP;
  constexpr int CH_U4 = CHW / 4;
  constexpr int NKC_TOT = WPP / 16;
  constexpr int KCW = NKC_TOT / 2;
  constexpr int ROWW = 66 * WPP;
  constexpr int ACTW = 6 * ROWW;
  constexpr int ALDS_W = (ACTW > 16384) ? ACTW : 16384;
  constexpr int R4_U4 = 4 * ROWW / 4;
  constexpr int R2_U4 = 2 * ROWW / 4;
  constexpr int AJ4 = (R4_U4 + 511) / 512;
  constexpr int LJ = (R2_U4 + 511) / 512;

  __shared__ unsigned Alds[ALDS_W];

  const int tid = threadIdx.x;
  const int lane = tid & 63;
  const int wav = tid >> 6;
  const int wr = wav >> 1;
  const int kh = wav & 1;
  const int l15 = lane & 15, q = lane >> 4;
  const int bid = blockIdx.x;
  const int n = bid & 7;
  const int ochalf = (bid >> 3) & 1;
  const int h0 = (bid >> 4) * 4;

  const uint4* wg = (const uint4*)(wb + (size_t)ochalf * 9 * CHW);
  const size_t abase = ((size_t)n * 66 + h0) * ROWW;
  const uint4* g0 = (const uint4*)(in0 + abase);
  const uint4* g1 = (const uint4*)(in1 + abase);

  // ---- head: stage rows 0..3 ----
#pragma unroll
  for (int j = 0; j < AJ4; ++j) {
    int i = tid + j * 512;
    if (i < R4_U4) {
      uint4 v = g0[i];
      if (DUAL) v = addpk4(v, g1[i]);
      *(uint4*)&Alds[4 * i] = v;
    }
  }

  uint4 wcur[4][KCW], wnxt[4][KCW];
#pragma unroll
  for (int m = 0; m < 4; ++m)
#pragma unroll
    for (int kc2 = 0; kc2 < KCW; ++kc2)
      wcur[m][kc2] = wg[(m * NKC_TOT + kh * KCW + kc2) * 64 + lane];

  __syncthreads();  // rows 0..3 visible

  f32x4 acc[4][4];
#pragma unroll
  for (int m = 0; m < 4; ++m)
#pragma unroll
    for (int p = 0; p < 4; ++p) acc[m][p] = (f32x4)0.f;

#pragma unroll
  for (int t = 0; t < 9; ++t) {
    if (t == 3) {  // seal rows 4,5 before first read
      asm volatile("s_waitcnt lgkmcnt(0)" ::: "memory");
      __builtin_amdgcn_s_barrier();
      __builtin_amdgcn_sched_barrier(0);
    }

    if (t < 8) {
#pragma unroll
      for (int m = 0; m < 4; ++m)
#pragma unroll
        for (int kc2 = 0; kc2 < KCW; ++kc2)
          wnxt[m][kc2] =
              wg[(t + 1) * CH_U4 + (m * NKC_TOT + kh * KCW + kc2) * 64 + lane];
    }

    const int dy = t / 3, dx = t % 3;
    const int arow = (wr + dy) * 66;

    __builtin_amdgcn_s_setprio(1);
#pragma unroll
    for (int kc2 = 0; kc2 < KCW; ++kc2) {
      const int kc = kh * KCW + kc2;
      bf16x8 a[4];
#pragma unroll
      for (int m = 0; m < 4; ++m) {
        U4 u; u.u = wcur[m][kc2]; a[m] = u.b;
      }
#pragma unroll
      for (int p = 0; p < 4; ++p) {
        int col = p * 16 + l15 + dx;
        U4 u;
        u.u = *(const uint4*)&Alds[(arow + col) * WPP +
                                   ((kc * 16 + q * 4) ^ ((col & 7) << 2))];
        bf16x8 b = u.b;
#pragma unroll
        for (int m = 0; m < 4; ++m)
          acc[m][p] =
              __builtin_amdgcn_mfma_f32_16x16x32_bf16(a[m], b, acc[m][p], 0, 0, 0);
      }
    }
    __builtin_amdgcn_s_setprio(0);

    if (t == 0) {  // commit rows 4,5 (L2-warm re-read)
#pragma unroll
      for (int j = 0; j < LJ; ++j) {
        int i = tid + j * 512;
        if (i < R2_U4) {
          uint4 v = g0[R4_U4 + i];
          if (DUAL) v = addpk4(v, g1[R4_U4 + i]);
          *(uint4*)&Alds[4 * (R4_U4 + i)] = v;
        }
      }
    }

#pragma unroll
    for (int m = 0; m < 4; ++m)
#pragma unroll
      for (int kc2 = 0; kc2 < KCW; ++kc2) wcur[m][kc2] = wnxt[m][kc2];
  }

  // ---- symmetric half-exchange reduction: wave-uniform branches, ALL
  //      acc indices compile-time constant (rule #20) ----
  __syncthreads();
  float* R = (float*)Alds;
  if (kh) {  // send p0,p1
#pragma unroll
    for (int m = 0; m < 4; ++m) {
      *(f32x4*)&R[(((wr * 2 + 1) * 8) + m * 2 + 0) * 256 + lane * 4] = acc[m][0];
      *(f32x4*)&R[(((wr * 2 + 1) * 8) + m * 2 + 1) * 256 + lane * 4] = acc[m][1];
    }
  } else {   // send p2,p3
#pragma unroll
    for (int m = 0; m < 4; ++m) {
      *(f32x4*)&R[(((wr * 2 + 0) * 8) + m * 2 + 0) * 256 + lane * 4] = acc[m][2];
      *(f32x4*)&R[(((wr * 2 + 0) * 8) + m * 2 + 1) * 256 + lane * 4] = acc[m][3];
    }
  }
  __syncthreads();
  if (kh) {  // own p2,p3
#pragma unroll
    for (int m = 0; m < 4; ++m) {
      acc[m][2] += *(const f32x4*)&R[(((wr * 2 + 0) * 8) + m * 2 + 0) * 256 + lane * 4];
      acc[m][3] += *(const f32x4*)&R[(((wr * 2 + 0) * 8) + m * 2 + 1) * 256 + lane * 4];
    }
  } else {   // own p0,p1
#pragma unroll
    for (int m = 0; m < 4; ++m) {
      acc[m][0] += *(const f32x4*)&R[(((wr * 2 + 1) * 8) + m * 2 + 0) * 256 + lane * 4];
      acc[m][1] += *(const f32x4*)&R[(((wr * 2 + 1) * 8) + m * 2 + 1) * 256 + lane * 4];
    }
  }

  // ---- epilogue: wave-uniform branch, constant p indices ----
  const int obase = ochalf * 64;
#define EPI_F32(P)                                                              \
  {                                                                             \
    _Pragma("unroll") for (int m = 0; m < 4; ++m) {                             \
      int oc0 = obase + m * 16 + q * 4;                                         \
      float4 bb = *(const float4*)&bias[oc0];                                   \
      int w = (P) * 16 + l15;                                                   \
      _Pragma("unroll") for (int j = 0; j < 4; ++j)                             \
          ((float*)outp)[(((size_t)n * 128 + oc0 + j) * 64 + (h0 + wr)) * 64 +  \
                         w] = acc[m][(P)][j] + ((const float*)&bb)[j] * bmult;  \
    }                                                                           \
  }
#define EPI_BF16(P)                                                             \
  {                                                                             \
    _Pragma("unroll") for (int m = 0; m < 4; ++m) {                             \
      int oc0 = obase + m * 16 + q * 4;                                         \
      float4 bb = *(const float4*)&bias[oc0];                                   \
      int icp0 = oc0 >> 1;                                                      \
      int w = (P) * 16 + l15;                                                   \
      int wp = w + 1;                                                           \
      unsigned lo = pk_bf16(acc[m][(P)][0] + bb.x * bmult,                      \
                            acc[m][(P)][1] + bb.y * bmult);                     \
      unsigned hi = pk_bf16(acc[m][(P)][2] + bb.z * bmult,                      \
                            acc[m][(P)][3] + bb.w * bmult);                     \
      int pos = icp0 ^ ((wp & 7) << 2);                                         \
      size_t base = (((size_t)n * 66 + (h0 + 1 + wr)) * 66 + wp) * 64;          \
      *(uint2*)&((unsigned*)outp)[base + pos] = make_uint2(lo, hi);             \
    }                                                                           \
  }
  if (OUTF32) {
    if (kh) { EPI_F32(2); EPI_F32(3); }
    else    { EPI_F32(0); EPI_F32(1); }
  } else {
    if (kh) { EPI_BF16(2); EPI_BF16(3); }
    else    { EPI_BF16(0); EPI_BF16(1); }
  }
#undef EPI_F32
#undef EPI_BF16
}

// ---------------- launch ------------------------------------------------------
extern "C" void kernel_launch(void* const* d_in, const int* in_sizes, int n_in,
                              void* d_out, int out_size, void* d_ws,
                              size_t ws_size, hipStream_t stream) {
  const float* x = (const float*)d_in[0];
  const float* W0 = (const float*)d_in[1];
  const float* b0 = (const float*)d_in[2];
  const float* Wn = (const float*)d_in[3];
  const float* bn = (const float*)d_in[4];

  const size_t ACTB = (size_t)8 * 66 * 66 * 64;
  const size_t TW = (size_t)8 * 66 * 66 * 32;
  unsigned* B0 = (unsigned*)d_ws;
  unsigned* B1 = B0 + ACTB;
  unsigned* B2 = B1 + ACTB;
  unsigned* T = B2 + ACTB;
  unsigned* Wb = T + TW;

  setup_all<<<256, 512, 0, stream>>>(x, W0, Wn, B0, B1, B2, T, Wb);

  dim3 grid(256), blk(512);
  const unsigned* Wnode = Wb + 36864;
  const size_t NW = 73728;

  conv_stage<64, false, false><<<grid, blk, 0, stream>>>(T, T, Wb, b0, 1.f, B0);
  conv_stage<128, false, false><<<grid, blk, 0, stream>>>(B0, B0, Wnode, bn + 0, 1.f, B1);
  conv_stage<128, true, false><<<grid, blk, 0, stream>>>(B0, B1, Wnode + 1 * NW, bn + 128, 2.f, B2);
  conv_stage<128, true, false><<<grid, blk, 0, stream>>>(B1, B2, Wnode + 2 * NW, bn + 256, 2.f, B0);
  conv_stage<128, true, false><<<grid, blk, 0, stream>>>(B2, B0, Wnode + 3 * NW, bn + 384, 2.f, B1);
  conv_stage<128, true, false><<<grid, blk, 0, stream>>>(B0, B1, Wnode + 4 * NW, bn + 512, 2.f, B2);
  conv_stage<128, true, true><<<grid, blk, 0, stream>>>(B1, B2, Wnode + 5 * NW, bn + 640, 2.f, d_out);

  (void)in_sizes; (void)n_in; (void)out_size; (void)ws_size;
}